// Round 5
// baseline (507.705 us; speedup 1.0000x reference)
//
#include <hip/hip_runtime.h>
#include <stdint.h>

// Problem constants (fixed by reference)
#define NN   65536      // nodes
#define BB   128        // graphs
#define NPGC 512        // nodes per graph
#define KSEL 256        // kept per graph
#define CC   128        // channels
#define EE   1114112    // edges incl. self loops

typedef unsigned short ushort_t;

// converted-weight table offsets (floats)
#define OFF_W1   0
#define OFF_Wp   16384
#define OFF_W2   32768
#define OFF_b1   49152
#define OFF_bp   49280
#define OFF_b2   49408
#define OFF_Wl1  49536
#define OFF_Wl2  49664
#define OFF_Wl3  49792
#define OFF_Wa   49920
#define OFF_ba   50176
#define OFF_bl1  50177
#define OFF_bl3  50178
#define WT_TOTAL 50179

__device__ inline float bf2f(ushort_t s){
  return __uint_as_float(((unsigned int)s) << 16);
}
__device__ inline ushort_t f2bf(float f){
  unsigned int u = __float_as_uint(f);
  u += 0x7fffu + ((u >> 16) & 1u);   // RNE
  return (ushort_t)(u >> 16);
}
template<typename T> __device__ inline float ldh(const T* p);
template<> __device__ inline float ldh<float>(const float* p){ return *p; }
template<> __device__ inline float ldh<ushort_t>(const ushort_t* p){ return bf2f(*p); }
template<typename T> __device__ inline void sth(T* p, float v);
template<> __device__ inline void sth<float>(float* p, float v){ *p = v; }
template<> __device__ inline void sth<ushort_t>(ushort_t* p, float v){ *p = f2bf(v); }

__device__ inline float wsum(float v){
  #pragma unroll
  for(int m = 32; m >= 1; m >>= 1) v += __shfl_xor(v, m, 64);
  return v;
}
__device__ inline float wmax(float v){
  #pragma unroll
  for(int m = 32; m >= 1; m >>= 1) v = fmaxf(v, __shfl_xor(v, m, 64));
  return v;
}

// edge_index may be int64 or int32. Under int64 (LE), the int32 view has
// zero high words; ei32[2*EE-1] = high(src[EE-1]=65535) = 0 iff int64,
// = dst[EE-1] = 65535 under int32.
__device__ inline bool ei_is64(const int* ei){ return ei[2 * EE - 1] == 0; }
__device__ inline int ei_src(const int* ei, int e, bool i64){
  return i64 ? ei[2 * (size_t)e] : ei[e];
}
__device__ inline int ei_dst(const int* ei, int e, bool i64){
  return i64 ? ei[2 * ((size_t)EE + e)] : ei[EE + e];
}

// ---- input float-dtype detection ------------------------------------------
// Probe 256 words of x. bits[14:7] of the word: under bf16 storage this is
// the low-halfword's exponent field -> in [0x70,0x85] for N(0,1) w.p. ~1.
// Under f32 storage it is uniform mantissa bits -> in range w.p. ~0.086.
__global__ void k_detect(const unsigned int* __restrict__ xw, int* __restrict__ flags){
  __shared__ int cnt[256];
  int t = threadIdx.x;
  unsigned w = xw[t];
  unsigned e = (w >> 7) & 0xffu;
  cnt[t] = (e >= 0x70u && e <= 0x85u) ? 1 : 0;
  __syncthreads();
  for(int s = 128; s > 0; s >>= 1){
    if(t < s) cnt[t] += cnt[t + s];
    __syncthreads();
  }
  if(t == 0) flags[0] = (cnt[0] < 128) ? 1 : 0;   // 1 = f32 inputs, 0 = bf16
}

// ---- convert all weights to f32 table -------------------------------------
__global__ void k_convert(const void* __restrict__ W1, const void* __restrict__ Wp,
                          const void* __restrict__ W2, const void* __restrict__ b1,
                          const void* __restrict__ bp, const void* __restrict__ b2,
                          const void* __restrict__ Wl1, const void* __restrict__ Wl2,
                          const void* __restrict__ Wl3, const void* __restrict__ Wa,
                          const void* __restrict__ ba, const void* __restrict__ bl1,
                          const void* __restrict__ bl3, float* __restrict__ wt,
                          const int* __restrict__ flags){
  int idx = blockIdx.x * 256 + threadIdx.x;
  bool is32 = (flags[0] == 1);
  const void* src; int so;
  if(idx < 16384){ src = W1; so = idx; }
  else if(idx < 32768){ src = Wp; so = idx - 16384; }
  else if(idx < 49152){ src = W2; so = idx - 32768; }
  else if(idx < 49280){ src = b1; so = idx - 49152; }
  else if(idx < 49408){ src = bp; so = idx - 49280; }
  else if(idx < 49536){ src = b2; so = idx - 49408; }
  else if(idx < 49664){ src = Wl1; so = idx - 49536; }
  else if(idx < 49792){ src = Wl2; so = idx - 49664; }
  else if(idx < 49920){ src = Wl3; so = idx - 49792; }
  else if(idx < 50176){ src = Wa; so = idx - 49920; }
  else if(idx == 50176){ src = ba; so = 0; }
  else if(idx == 50177){ src = bl1; so = 0; }
  else if(idx == 50178){ src = bl3; so = 0; }
  else return;
  float v = is32 ? ((const float*)src)[so] : bf2f(((const ushort_t*)src)[so]);
  wt[idx] = v;
}

// ---- CSR build -------------------------------------------------------------
__global__ void k_zero(int* __restrict__ p){
  p[blockIdx.x * 256 + threadIdx.x] = 0;
}

__global__ void k_count(const int* __restrict__ ei, int* __restrict__ deg){
  int e = blockIdx.x * 256 + threadIdx.x;
  bool i64 = ei_is64(ei);
  int d = ei_dst(ei, e, i64);
  if((unsigned)d < NN) atomicAdd(&deg[d], 1);
}

__global__ void k_scan_block(const int* __restrict__ in, int* __restrict__ out_excl,
                             int* __restrict__ bsum){
  __shared__ int s[256];
  int b = blockIdx.x, t = threadIdx.x, idx = b * 256 + t;
  int v = in[idx];
  s[t] = v; __syncthreads();
  #pragma unroll
  for(int off = 1; off < 256; off <<= 1){
    int u = (t >= off) ? s[t - off] : 0;
    __syncthreads();
    s[t] += u;
    __syncthreads();
  }
  out_excl[idx] = s[t] - v;
  if(t == 255) bsum[b] = s[t];
}

__global__ void k_scan_add(const int* __restrict__ bexc, int* __restrict__ offs,
                           int* __restrict__ cursor){
  int b = blockIdx.x, t = threadIdx.x, idx = b * 256 + t;
  int o = offs[idx] + bexc[b];
  offs[idx] = o; cursor[idx] = o;
  if(idx == 0) offs[NN] = EE;
}

__global__ void k_fill(const int* __restrict__ ei, int* __restrict__ cursor,
                       int* __restrict__ csr){
  int e = blockIdx.x * 256 + threadIdx.x;
  bool i64 = ei_is64(ei);
  int d = ei_dst(ei, e, i64);
  int s = ei_src(ei, e, i64);
  if((unsigned)d < NN){
    int p = atomicAdd(&cursor[d], 1);
    csr[p] = s;
  }
}

// ---- precompute v = Wp @ Wa[:128], c = dot(bp, Wa[:128]) -------------------
__global__ void k_prep(const float* __restrict__ wt, float* __restrict__ vvec,
                       float* __restrict__ cval){
  int t = threadIdx.x; // 128
  const float* Wpf = wt + OFF_Wp;
  const float* Waf = wt + OFF_Wa;
  float acc = 0.f;
  for(int o = 0; o < CC; o++) acc = fmaf(Wpf[t * CC + o], Waf[o], acc);
  vvec[t] = acc;
  __shared__ float red[128];
  red[t] = wt[OFF_bp + t] * Waf[t];
  __syncthreads();
  for(int s2 = 64; s2 > 0; s2 >>= 1){
    if(t < s2) red[t] += red[t + s2];
    __syncthreads();
  }
  if(t == 0) cval[0] = red[0];
}

// ---- h = relu(x @ W1 + b1), hs = h @ Wa[128:256] ---------------------------
template<typename T>
__launch_bounds__(128)
__global__ void k_gemm(const void* __restrict__ x, const float* __restrict__ wt,
                       const int* __restrict__ flags,
                       T* __restrict__ h, float* __restrict__ hs){
  __shared__ float xr[4][CC];
  __shared__ float red[8];
  const float* W1f = wt + OFF_W1;
  int t = threadIdx.x;
  bool is32 = (flags[0] == 1);
  float b1t  = wt[OFF_b1 + t];
  float wa2t = wt[OFF_Wa + 128 + t];
  int lane = t & 63, wid = t >> 6;
  for(int rg = blockIdx.x; rg < NN / 4; rg += gridDim.x){
    if(is32){
      float4 u = ((const float4*)x)[(size_t)rg * 128 + t];
      float* d = &xr[t >> 5][(t & 31) * 4];
      d[0] = u.x; d[1] = u.y; d[2] = u.z; d[3] = u.w;
    }else if(t < 64){
      uint4 u = ((const uint4*)x)[(size_t)rg * 64 + t];
      float* d = &xr[t >> 4][(t & 15) * 8];
      d[0] = bf2f((ushort_t)(u.x & 0xffff)); d[1] = bf2f((ushort_t)(u.x >> 16));
      d[2] = bf2f((ushort_t)(u.y & 0xffff)); d[3] = bf2f((ushort_t)(u.y >> 16));
      d[4] = bf2f((ushort_t)(u.z & 0xffff)); d[5] = bf2f((ushort_t)(u.z >> 16));
      d[6] = bf2f((ushort_t)(u.w & 0xffff)); d[7] = bf2f((ushort_t)(u.w >> 16));
    }
    __syncthreads();
    float a0 = b1t, a1 = b1t, a2 = b1t, a3 = b1t;
    #pragma unroll 4
    for(int k = 0; k < CC; k++){
      float w = W1f[k * CC + t];   // coalesced, L1/L2-resident
      a0 = fmaf(xr[0][k], w, a0);
      a1 = fmaf(xr[1][k], w, a1);
      a2 = fmaf(xr[2][k], w, a2);
      a3 = fmaf(xr[3][k], w, a3);
    }
    a0 = fmaxf(a0, 0.f); a1 = fmaxf(a1, 0.f); a2 = fmaxf(a2, 0.f); a3 = fmaxf(a3, 0.f);
    size_t rbase = (size_t)rg * 4 * CC;
    sth(&h[rbase + t], a0);
    sth(&h[rbase + CC + t], a1);
    sth(&h[rbase + 2 * CC + t], a2);
    sth(&h[rbase + 3 * CC + t], a3);
    float p0 = wsum(a0 * wa2t), p1 = wsum(a1 * wa2t);
    float p2 = wsum(a2 * wa2t), p3 = wsum(a3 * wa2t);
    if(lane == 0){ red[0 + wid] = p0; red[2 + wid] = p1; red[4 + wid] = p2; red[6 + wid] = p3; }
    __syncthreads();
    if(t < 4) hs[rg * 4 + t] = red[t * 2] + red[t * 2 + 1];
    __syncthreads();
  }
}

// ---- per-node: segment max -> q -> softmax -> xc, LEConv node terms --------
template<typename T>
__launch_bounds__(256)
__global__ void k_edge(const T* __restrict__ h, const float* __restrict__ hs,
                       const int* __restrict__ offs, const int* __restrict__ csr,
                       const float* __restrict__ vvec, const float* __restrict__ cval,
                       const float* __restrict__ wt,
                       T* __restrict__ xc, float* __restrict__ a_s,
                       float* __restrict__ fitp){
  int gid = blockIdx.x * blockDim.x + threadIdx.x;
  int i = gid >> 6;
  int lane = threadIdx.x & 63;
  int beg = offs[i], end = offs[i + 1];
  int c0 = lane, c1 = lane + 64;
  // pass 1: x_q = max over in-neighbors (h >= 0 so 0-init matches segment_max)
  float mx0 = 0.f, mx1 = 0.f;
  for(int e = beg; e < end; e++){
    int s = csr[e];
    if((unsigned)s >= NN) continue;
    const T* hr = h + (size_t)s * CC;
    mx0 = fmaxf(mx0, ldh(&hr[c0]));
    mx1 = fmaxf(mx1, ldh(&hr[c1]));
  }
  float q = wsum(mx0 * vvec[c0] + mx1 * vvec[c1]) + cval[0];
  float bav = wt[OFF_ba];
  // pass 2: max score
  float sm = -1e30f;
  for(int e = beg + lane; e < end; e += 64){
    int s = csr[e];
    if((unsigned)s >= NN) continue;
    float sc = q + hs[s] + bav;
    sc = sc > 0.f ? sc : 0.2f * sc;
    sm = fmaxf(sm, sc);
  }
  sm = wmax(sm);
  if(sm < -1e29f) sm = 0.f;
  // pass 3: softmax-weighted aggregation
  float acc0 = 0.f, acc1 = 0.f, ssum = 0.f;
  for(int e = beg; e < end; e++){
    int s = csr[e];
    if((unsigned)s >= NN) continue;
    float sc = q + hs[s] + bav;
    sc = sc > 0.f ? sc : 0.2f * sc;
    float es = expf(sc - sm);
    ssum += es;
    const T* hr = h + (size_t)s * CC;
    acc0 = fmaf(es, ldh(&hr[c0]), acc0);
    acc1 = fmaf(es, ldh(&hr[c1]), acc1);
  }
  float inv = (ssum > 0.f) ? (1.f / ssum) : 0.f;
  float xc0 = acc0 * inv, xc1 = acc1 * inv;
  sth(&xc[(size_t)i * CC + c0], xc0);
  sth(&xc[(size_t)i * CC + c1], xc1);
  float d1 = wsum(xc0 * wt[OFF_Wl1 + c0] + xc1 * wt[OFF_Wl1 + c1]);
  float d2 = wsum(xc0 * wt[OFF_Wl2 + c0] + xc1 * wt[OFF_Wl2 + c1]);
  float d3 = wsum(xc0 * wt[OFF_Wl3 + c0] + xc1 * wt[OFF_Wl3 + c1]);
  if(lane == 0){
    a_s[i]  = d1 + wt[OFF_bl1];
    fitp[i] = -(float)(end - beg) * d2 + d3 + wt[OFF_bl3];
  }
}

// ---- fit[i] = sigmoid(sum_j a[src] + fitp[i]) ------------------------------
__global__ void k_fit(const int* __restrict__ offs, const int* __restrict__ csr,
                      const float* __restrict__ a_s, const float* __restrict__ fitp,
                      float* __restrict__ fit){
  int i = blockIdx.x * 256 + threadIdx.x;
  float f = fitp[i];
  int e1 = offs[i + 1];
  for(int e = offs[i]; e < e1; e++){
    int s = csr[e];
    if((unsigned)s < NN) f += a_s[s];
  }
  fit[i] = 1.f / (1.f + expf(-f));
}

// ---- per-graph top-K + sum of xc*fit over selected -------------------------
template<typename T>
__launch_bounds__(512)
__global__ void k_select(const float* __restrict__ fit, const T* __restrict__ xc,
                         float* __restrict__ gsum){
  __shared__ float fl[NPGC];
  __shared__ int   sel[NPGC];
  __shared__ float part[NPGC];
  int g = blockIdx.x, t = threadIdx.x;
  fl[t] = fit[g * NPGC + t];
  __syncthreads();
  float ft = fl[t];
  int r = 0;
  for(int j = 0; j < NPGC; j++){
    float fj = fl[j];
    if(fj > ft || (fj == ft && j < t)) r++;
  }
  sel[t] = (r < KSEL) ? 1 : 0;
  __syncthreads();
  int c = t & (CC - 1), grp = t >> 7;
  float acc = 0.f;
  int nb = grp * 128;
  for(int n = nb; n < nb + 128; n++){
    if(sel[n]) acc = fmaf(ldh(&xc[((size_t)g * NPGC + n) * CC + c]), fl[n], acc);
  }
  part[t] = acc;
  __syncthreads();
  if(t < CC) gsum[g * CC + t] = part[t] + part[t + 128] + part[t + 256] + part[t + 384];
}

// ---- out[g] = (gsum/K) @ W2 + b2  (f32 out — reference output is float32) --
__global__ void k_out(const float* __restrict__ gsum, const float* __restrict__ wt,
                      const int* __restrict__ flags, float* __restrict__ out){
  __shared__ float gs[CC];
  int g = blockIdx.x, t = threadIdx.x;
  gs[t] = gsum[g * CC + t] * (1.f / (float)KSEL);
  __syncthreads();
  float acc = wt[OFF_b2 + t];
  for(int k = 0; k < CC; k++) acc = fmaf(gs[k], wt[OFF_W2 + k * CC + t], acc);
  // sentinel: 7.0 = NaN with bf16-detected inputs, 8.0 = NaN with f32-detected
  if(!(fabsf(acc) < 1e30f)) acc = 7.0f + (float)flags[0];
  out[g * CC + t] = acc;
}

extern "C" void kernel_launch(void* const* d_in, const int* in_sizes, int n_in,
                              void* d_out, int out_size, void* d_ws, size_t ws_size,
                              hipStream_t stream){
  const void* x   = d_in[0];
  const void* W1  = d_in[1];
  const void* b1  = d_in[2];
  const void* Wp  = d_in[3];
  const void* bp  = d_in[4];
  const void* Wa  = d_in[5];
  const void* ba  = d_in[6];
  const void* Wl1 = d_in[7];
  const void* bl1 = d_in[8];
  const void* Wl2 = d_in[9];
  const void* Wl3 = d_in[10];
  const void* bl3 = d_in[11];
  const void* W2  = d_in[12];
  const void* b2  = d_in[13];
  const int* ei   = (const int*)d_in[14];
  float* out = (float*)d_out;

  // ---- workspace layout (fixed part ~6.5 MB) ----
  char* base = (char*)d_ws;
  size_t off = 0;
  #define TAKE(bytes) (off += (bytes), (void*)(base + off - (bytes)))
  float* hs    = (float*)TAKE((size_t)NN * 4);
  float* a_s   = (float*)TAKE((size_t)NN * 4);
  float* fitp  = (float*)TAKE((size_t)NN * 4);
  float* fit   = (float*)TAKE((size_t)NN * 4);
  float* vvec  = (float*)TAKE(128 * 4);
  float* cval  = (float*)TAKE(128 * 4);
  float* gsum  = (float*)TAKE((size_t)BB * CC * 4);
  int*   offs  = (int*)TAKE((size_t)(NN + 128) * 4);
  int*   deg   = (int*)TAKE((size_t)NN * 4);      // reused as cursor
  int*   bsum  = (int*)TAKE(256 * 4);
  int*   bexc  = (int*)TAKE(256 * 4);
  int*   scr   = (int*)TAKE(256 * 4);
  float* wt    = (float*)TAKE((size_t)(WT_TOTAL + 64) * 4);
  int*   flags = (int*)TAKE(64 * 4);
  int*   csr   = (int*)TAKE((size_t)EE * 4);
  size_t fixed = off;
  #undef TAKE
  int* cursor = deg;

  bool f32plan = (ws_size >= fixed + (size_t)2 * NN * CC * 4);

  k_detect<<<1, 256, 0, stream>>>((const unsigned int*)x, flags);
  k_convert<<<(WT_TOTAL + 255) / 256, 256, 0, stream>>>(W1, Wp, W2, b1, bp, b2,
                                                        Wl1, Wl2, Wl3, Wa, ba,
                                                        bl1, bl3, wt, flags);
  k_prep<<<1, 128, 0, stream>>>(wt, vvec, cval);
  k_zero<<<NN / 256, 256, 0, stream>>>(deg);
  k_count<<<EE / 256, 256, 0, stream>>>(ei, deg);
  k_scan_block<<<256, 256, 0, stream>>>(deg, offs, bsum);
  k_scan_block<<<1, 256, 0, stream>>>(bsum, bexc, scr);
  k_scan_add<<<256, 256, 0, stream>>>(bexc, offs, cursor);
  k_fill<<<EE / 256, 256, 0, stream>>>(ei, cursor, csr);

  if(f32plan){
    float* h  = (float*)(base + fixed);
    float* xc = h + (size_t)NN * CC;
    k_gemm<float><<<2048, 128, 0, stream>>>(x, wt, flags, h, hs);
    k_edge<float><<<NN / 4, 256, 0, stream>>>(h, hs, offs, csr, vvec, cval, wt,
                                              xc, a_s, fitp);
    k_fit<<<NN / 256, 256, 0, stream>>>(offs, csr, a_s, fitp, fit);
    k_select<float><<<BB, 512, 0, stream>>>(fit, xc, gsum);
  }else{
    ushort_t* h  = (ushort_t*)(base + fixed);
    ushort_t* xc = h + (size_t)NN * CC;
    k_gemm<ushort_t><<<2048, 128, 0, stream>>>(x, wt, flags, h, hs);
    k_edge<ushort_t><<<NN / 4, 256, 0, stream>>>(h, hs, offs, csr, vvec, cval, wt,
                                                 xc, a_s, fitp);
    k_fit<<<NN / 256, 256, 0, stream>>>(offs, csr, a_s, fitp, fit);
    k_select<ushort_t><<<BB, 512, 0, stream>>>(fit, xc, gsum);
  }
  k_out<<<BB, 128, 0, stream>>>(gsum, wt, flags, out);
}

// Round 6
// 413.166 us; speedup vs baseline: 1.2288x; 1.2288x over previous
//
#include <hip/hip_runtime.h>
#include <stdint.h>

// Problem constants (fixed by reference)
#define NN   65536      // nodes
#define BB   128        // graphs
#define NPGC 512        // nodes per graph
#define KSEL 256        // kept per graph
#define CC   128        // channels
#define EE   1114112    // edges incl. self loops

typedef unsigned short ushort_t;

// converted-weight table offsets (floats)
#define OFF_W1   0
#define OFF_Wp   16384
#define OFF_W2   32768
#define OFF_b1   49152
#define OFF_bp   49280
#define OFF_b2   49408
#define OFF_Wl1  49536
#define OFF_Wl2  49664
#define OFF_Wl3  49792
#define OFF_Wa   49920
#define OFF_ba   50176
#define OFF_bl1  50177
#define OFF_bl3  50178
#define WT_TOTAL 50179

__device__ inline float bf2f(ushort_t s){
  return __uint_as_float(((unsigned int)s) << 16);
}
__device__ inline ushort_t f2bf(float f){
  unsigned int u = __float_as_uint(f);
  u += 0x7fffu + ((u >> 16) & 1u);   // RNE
  return (ushort_t)(u >> 16);
}
template<typename T> __device__ inline float ldh(const T* p);
template<> __device__ inline float ldh<float>(const float* p){ return *p; }
template<> __device__ inline float ldh<ushort_t>(const ushort_t* p){ return bf2f(*p); }
template<typename T> __device__ inline void sth(T* p, float v);
template<> __device__ inline void sth<float>(float* p, float v){ *p = v; }
template<> __device__ inline void sth<ushort_t>(ushort_t* p, float v){ *p = f2bf(v); }

__device__ inline float wsum(float v){
  #pragma unroll
  for(int m = 32; m >= 1; m >>= 1) v += __shfl_xor(v, m, 64);
  return v;
}
__device__ inline float wmax(float v){
  #pragma unroll
  for(int m = 32; m >= 1; m >>= 1) v = fmaxf(v, __shfl_xor(v, m, 64));
  return v;
}

// edge_index may be int64 or int32. Under int64 (LE), the int32 view has
// zero high words; ei32[2*EE-1] = high(src[EE-1]=65535) = 0 iff int64,
// = dst[EE-1] = 65535 under int32.
__device__ inline bool ei_is64(const int* ei){ return ei[2 * EE - 1] == 0; }
__device__ inline int ei_src(const int* ei, int e, bool i64){
  return i64 ? ei[2 * (size_t)e] : ei[e];
}
__device__ inline int ei_dst(const int* ei, int e, bool i64){
  return i64 ? ei[2 * ((size_t)EE + e)] : ei[EE + e];
}

// ---- input float-dtype detection ------------------------------------------
__global__ void k_detect(const unsigned int* __restrict__ xw, int* __restrict__ flags){
  __shared__ int cnt[256];
  int t = threadIdx.x;
  unsigned w = xw[t];
  unsigned e = (w >> 7) & 0xffu;
  cnt[t] = (e >= 0x70u && e <= 0x85u) ? 1 : 0;
  __syncthreads();
  for(int s = 128; s > 0; s >>= 1){
    if(t < s) cnt[t] += cnt[t + s];
    __syncthreads();
  }
  if(t == 0) flags[0] = (cnt[0] < 128) ? 1 : 0;   // 1 = f32 inputs, 0 = bf16
}

// ---- convert all weights to f32 table -------------------------------------
__global__ void k_convert(const void* __restrict__ W1, const void* __restrict__ Wp,
                          const void* __restrict__ W2, const void* __restrict__ b1,
                          const void* __restrict__ bp, const void* __restrict__ b2,
                          const void* __restrict__ Wl1, const void* __restrict__ Wl2,
                          const void* __restrict__ Wl3, const void* __restrict__ Wa,
                          const void* __restrict__ ba, const void* __restrict__ bl1,
                          const void* __restrict__ bl3, float* __restrict__ wt,
                          const int* __restrict__ flags){
  int idx = blockIdx.x * 256 + threadIdx.x;
  bool is32 = (flags[0] == 1);
  const void* src; int so;
  if(idx < 16384){ src = W1; so = idx; }
  else if(idx < 32768){ src = Wp; so = idx - 16384; }
  else if(idx < 49152){ src = W2; so = idx - 32768; }
  else if(idx < 49280){ src = b1; so = idx - 49152; }
  else if(idx < 49408){ src = bp; so = idx - 49280; }
  else if(idx < 49536){ src = b2; so = idx - 49408; }
  else if(idx < 49664){ src = Wl1; so = idx - 49536; }
  else if(idx < 49792){ src = Wl2; so = idx - 49664; }
  else if(idx < 49920){ src = Wl3; so = idx - 49792; }
  else if(idx < 50176){ src = Wa; so = idx - 49920; }
  else if(idx == 50176){ src = ba; so = 0; }
  else if(idx == 50177){ src = bl1; so = 0; }
  else if(idx == 50178){ src = bl3; so = 0; }
  else return;
  float v = is32 ? ((const float*)src)[so] : bf2f(((const ushort_t*)src)[so]);
  wt[idx] = v;
}

// ---- CSR build -------------------------------------------------------------
__global__ void k_zero(int* __restrict__ p){
  p[blockIdx.x * 256 + threadIdx.x] = 0;
}

__global__ void k_count(const int* __restrict__ ei, int* __restrict__ deg){
  int e = blockIdx.x * 256 + threadIdx.x;
  bool i64 = ei_is64(ei);
  int d = ei_dst(ei, e, i64);
  if((unsigned)d < NN) atomicAdd(&deg[d], 1);
}

__global__ void k_scan_block(const int* __restrict__ in, int* __restrict__ out_excl,
                             int* __restrict__ bsum){
  __shared__ int s[256];
  int b = blockIdx.x, t = threadIdx.x, idx = b * 256 + t;
  int v = in[idx];
  s[t] = v; __syncthreads();
  #pragma unroll
  for(int off = 1; off < 256; off <<= 1){
    int u = (t >= off) ? s[t - off] : 0;
    __syncthreads();
    s[t] += u;
    __syncthreads();
  }
  out_excl[idx] = s[t] - v;
  if(t == 255) bsum[b] = s[t];
}

__global__ void k_scan_add(const int* __restrict__ bexc, int* __restrict__ offs,
                           int* __restrict__ cursor){
  int b = blockIdx.x, t = threadIdx.x, idx = b * 256 + t;
  int o = offs[idx] + bexc[b];
  offs[idx] = o; cursor[idx] = o;
  if(idx == 0) offs[NN] = EE;
}

__global__ void k_fill(const int* __restrict__ ei, int* __restrict__ cursor,
                       int* __restrict__ csr){
  int e = blockIdx.x * 256 + threadIdx.x;
  bool i64 = ei_is64(ei);
  int d = ei_dst(ei, e, i64);
  int s = ei_src(ei, e, i64);
  if((unsigned)d < NN){
    int p = atomicAdd(&cursor[d], 1);
    csr[p] = s;
  }
}

// ---- precompute v = Wp @ Wa[:128], c = dot(bp, Wa[:128]) -------------------
__global__ void k_prep(const float* __restrict__ wt, float* __restrict__ vvec,
                       float* __restrict__ cval){
  int t = threadIdx.x; // 128
  const float* Wpf = wt + OFF_Wp;
  const float* Waf = wt + OFF_Wa;
  float acc = 0.f;
  for(int o = 0; o < CC; o++) acc = fmaf(Wpf[t * CC + o], Waf[o], acc);
  vvec[t] = acc;
  __shared__ float red[128];
  red[t] = wt[OFF_bp + t] * Waf[t];
  __syncthreads();
  for(int s2 = 64; s2 > 0; s2 >>= 1){
    if(t < s2) red[t] += red[t + s2];
    __syncthreads();
  }
  if(t == 0) cval[0] = red[0];
}

// ---- h = relu(x @ W1 + b1), hs = h @ Wa[128:256] ---------------------------
template<typename T>
__launch_bounds__(128)
__global__ void k_gemm(const void* __restrict__ x, const float* __restrict__ wt,
                       const int* __restrict__ flags,
                       T* __restrict__ h, float* __restrict__ hs){
  __shared__ float xr[4][CC];
  __shared__ float red[8];
  const float* W1f = wt + OFF_W1;
  int t = threadIdx.x;
  bool is32 = (flags[0] == 1);
  float b1t  = wt[OFF_b1 + t];
  float wa2t = wt[OFF_Wa + 128 + t];
  int lane = t & 63, wid = t >> 6;
  for(int rg = blockIdx.x; rg < NN / 4; rg += gridDim.x){
    if(is32){
      float4 u = ((const float4*)x)[(size_t)rg * 128 + t];
      float* d = &xr[t >> 5][(t & 31) * 4];
      d[0] = u.x; d[1] = u.y; d[2] = u.z; d[3] = u.w;
    }else if(t < 64){
      uint4 u = ((const uint4*)x)[(size_t)rg * 64 + t];
      float* d = &xr[t >> 4][(t & 15) * 8];
      d[0] = bf2f((ushort_t)(u.x & 0xffff)); d[1] = bf2f((ushort_t)(u.x >> 16));
      d[2] = bf2f((ushort_t)(u.y & 0xffff)); d[3] = bf2f((ushort_t)(u.y >> 16));
      d[4] = bf2f((ushort_t)(u.z & 0xffff)); d[5] = bf2f((ushort_t)(u.z >> 16));
      d[6] = bf2f((ushort_t)(u.w & 0xffff)); d[7] = bf2f((ushort_t)(u.w >> 16));
    }
    __syncthreads();
    float a0 = b1t, a1 = b1t, a2 = b1t, a3 = b1t;
    #pragma unroll 4
    for(int k = 0; k < CC; k++){
      float w = W1f[k * CC + t];
      a0 = fmaf(xr[0][k], w, a0);
      a1 = fmaf(xr[1][k], w, a1);
      a2 = fmaf(xr[2][k], w, a2);
      a3 = fmaf(xr[3][k], w, a3);
    }
    a0 = fmaxf(a0, 0.f); a1 = fmaxf(a1, 0.f); a2 = fmaxf(a2, 0.f); a3 = fmaxf(a3, 0.f);
    size_t rbase = (size_t)rg * 4 * CC;
    sth(&h[rbase + t], a0);
    sth(&h[rbase + CC + t], a1);
    sth(&h[rbase + 2 * CC + t], a2);
    sth(&h[rbase + 3 * CC + t], a3);
    float p0 = wsum(a0 * wa2t), p1 = wsum(a1 * wa2t);
    float p2 = wsum(a2 * wa2t), p3 = wsum(a3 * wa2t);
    if(lane == 0){ red[0 + wid] = p0; red[2 + wid] = p1; red[4 + wid] = p2; red[6 + wid] = p3; }
    __syncthreads();
    if(t < 4) hs[rg * 4 + t] = red[t * 2] + red[t * 2 + 1];
    __syncthreads();
  }
}

// ---- per-node fused gather: max -> q -> softmax -> xc + LEConv terms -------
// One wave per node. Lane handles channels (2*lane, 2*lane+1) -> one float2
// gather covers the full 128-ch row per edge. Unroll-4 for MLP.
__launch_bounds__(256)
__global__ void k_edge_f32(const float* __restrict__ h, const float* __restrict__ hs,
                           const int* __restrict__ offs, const int* __restrict__ csr,
                           const float* __restrict__ vvec, const float* __restrict__ cval,
                           const float* __restrict__ wt,
                           float* __restrict__ xc, float* __restrict__ a_s,
                           float* __restrict__ fitp){
  int i = (blockIdx.x * blockDim.x + threadIdx.x) >> 6;
  int lane = threadIdx.x & 63;
  int beg = offs[i], end = offs[i + 1];
  int c = lane * 2;
  float bav = wt[OFF_ba];
  // pass 1: elementwise max over in-neighbors (h>=0) + max of hs
  float mx0 = 0.f, mx1 = 0.f, mhs = -1e30f;
  int e = beg;
  for(; e + 4 <= end; e += 4){
    int s0 = csr[e], s1 = csr[e + 1], s2 = csr[e + 2], s3 = csr[e + 3];
    float2 a0 = *(const float2*)(h + (size_t)s0 * CC + c);
    float2 a1 = *(const float2*)(h + (size_t)s1 * CC + c);
    float2 a2 = *(const float2*)(h + (size_t)s2 * CC + c);
    float2 a3 = *(const float2*)(h + (size_t)s3 * CC + c);
    float h0 = hs[s0], h1 = hs[s1], h2 = hs[s2], h3 = hs[s3];
    mx0 = fmaxf(fmaxf(fmaxf(mx0, a0.x), a1.x), fmaxf(a2.x, a3.x));
    mx1 = fmaxf(fmaxf(fmaxf(mx1, a0.y), a1.y), fmaxf(a2.y, a3.y));
    mhs = fmaxf(fmaxf(fmaxf(mhs, h0), h1), fmaxf(h2, h3));
  }
  for(; e < end; e++){
    int s0 = csr[e];
    float2 a0 = *(const float2*)(h + (size_t)s0 * CC + c);
    mx0 = fmaxf(mx0, a0.x); mx1 = fmaxf(mx1, a0.y);
    mhs = fmaxf(mhs, hs[s0]);
  }
  float2 vv = *(const float2*)(vvec + c);
  float q = wsum(mx0 * vv.x + mx1 * vv.y) + cval[0];
  // lrelu monotone: max_e lrelu(q+hs_e+ba) == lrelu(q + max_hs + ba)
  float smr = q + mhs + bav;
  float sm = smr > 0.f ? smr : 0.2f * smr;
  // pass 2: softmax-weighted aggregation
  float acc0 = 0.f, acc1 = 0.f, ssum = 0.f;
  e = beg;
  for(; e + 4 <= end; e += 4){
    int s0 = csr[e], s1 = csr[e + 1], s2 = csr[e + 2], s3 = csr[e + 3];
    float h0 = hs[s0], h1 = hs[s1], h2 = hs[s2], h3 = hs[s3];
    float2 a0 = *(const float2*)(h + (size_t)s0 * CC + c);
    float2 a1 = *(const float2*)(h + (size_t)s1 * CC + c);
    float2 a2 = *(const float2*)(h + (size_t)s2 * CC + c);
    float2 a3 = *(const float2*)(h + (size_t)s3 * CC + c);
    float r0 = q + h0 + bav; r0 = (r0 > 0.f ? r0 : 0.2f * r0) - sm;
    float r1 = q + h1 + bav; r1 = (r1 > 0.f ? r1 : 0.2f * r1) - sm;
    float r2 = q + h2 + bav; r2 = (r2 > 0.f ? r2 : 0.2f * r2) - sm;
    float r3 = q + h3 + bav; r3 = (r3 > 0.f ? r3 : 0.2f * r3) - sm;
    float e0 = __expf(r0), e1 = __expf(r1), e2 = __expf(r2), e3 = __expf(r3);
    ssum += (e0 + e1) + (e2 + e3);
    acc0 = fmaf(e0, a0.x, fmaf(e1, a1.x, fmaf(e2, a2.x, fmaf(e3, a3.x, acc0))));
    acc1 = fmaf(e0, a0.y, fmaf(e1, a1.y, fmaf(e2, a2.y, fmaf(e3, a3.y, acc1))));
  }
  for(; e < end; e++){
    int s0 = csr[e];
    float h0 = hs[s0];
    float2 a0 = *(const float2*)(h + (size_t)s0 * CC + c);
    float r0 = q + h0 + bav; r0 = (r0 > 0.f ? r0 : 0.2f * r0) - sm;
    float e0 = __expf(r0);
    ssum += e0;
    acc0 = fmaf(e0, a0.x, acc0);
    acc1 = fmaf(e0, a0.y, acc1);
  }
  float inv = (ssum > 0.f) ? (1.f / ssum) : 0.f;
  float xc0 = acc0 * inv, xc1 = acc1 * inv;
  float2 st; st.x = xc0; st.y = xc1;
  *(float2*)(xc + (size_t)i * CC + c) = st;
  float2 w1 = *(const float2*)(wt + OFF_Wl1 + c);
  float2 w2 = *(const float2*)(wt + OFF_Wl2 + c);
  float2 w3 = *(const float2*)(wt + OFF_Wl3 + c);
  float d1 = wsum(xc0 * w1.x + xc1 * w1.y);
  float d2 = wsum(xc0 * w2.x + xc1 * w2.y);
  float d3 = wsum(xc0 * w3.x + xc1 * w3.y);
  if(lane == 0){
    a_s[i]  = d1 + wt[OFF_bl1];
    fitp[i] = -(float)(end - beg) * d2 + d3 + wt[OFF_bl3];
  }
}

// ---- generic (bf16-h fallback) version ------------------------------------
template<typename T>
__launch_bounds__(256)
__global__ void k_edge(const T* __restrict__ h, const float* __restrict__ hs,
                       const int* __restrict__ offs, const int* __restrict__ csr,
                       const float* __restrict__ vvec, const float* __restrict__ cval,
                       const float* __restrict__ wt,
                       T* __restrict__ xc, float* __restrict__ a_s,
                       float* __restrict__ fitp){
  int gid = blockIdx.x * blockDim.x + threadIdx.x;
  int i = gid >> 6;
  int lane = threadIdx.x & 63;
  int beg = offs[i], end = offs[i + 1];
  int c0 = lane, c1 = lane + 64;
  float mx0 = 0.f, mx1 = 0.f, mhs = -1e30f;
  for(int e = beg; e < end; e++){
    int s = csr[e];
    const T* hr = h + (size_t)s * CC;
    mx0 = fmaxf(mx0, ldh(&hr[c0]));
    mx1 = fmaxf(mx1, ldh(&hr[c1]));
    mhs = fmaxf(mhs, hs[s]);
  }
  float q = wsum(mx0 * vvec[c0] + mx1 * vvec[c1]) + cval[0];
  float bav = wt[OFF_ba];
  float smr = q + mhs + bav;
  float sm = smr > 0.f ? smr : 0.2f * smr;
  float acc0 = 0.f, acc1 = 0.f, ssum = 0.f;
  for(int e = beg; e < end; e++){
    int s = csr[e];
    float sc = q + hs[s] + bav;
    sc = sc > 0.f ? sc : 0.2f * sc;
    float es = __expf(sc - sm);
    ssum += es;
    const T* hr = h + (size_t)s * CC;
    acc0 = fmaf(es, ldh(&hr[c0]), acc0);
    acc1 = fmaf(es, ldh(&hr[c1]), acc1);
  }
  float inv = (ssum > 0.f) ? (1.f / ssum) : 0.f;
  float xc0 = acc0 * inv, xc1 = acc1 * inv;
  sth(&xc[(size_t)i * CC + c0], xc0);
  sth(&xc[(size_t)i * CC + c1], xc1);
  float d1 = wsum(xc0 * wt[OFF_Wl1 + c0] + xc1 * wt[OFF_Wl1 + c1]);
  float d2 = wsum(xc0 * wt[OFF_Wl2 + c0] + xc1 * wt[OFF_Wl2 + c1]);
  float d3 = wsum(xc0 * wt[OFF_Wl3 + c0] + xc1 * wt[OFF_Wl3 + c1]);
  if(lane == 0){
    a_s[i]  = d1 + wt[OFF_bl1];
    fitp[i] = -(float)(end - beg) * d2 + d3 + wt[OFF_bl3];
  }
}

// ---- fit[i] = sigmoid(sum_j a[src] + fitp[i]) ------------------------------
__global__ void k_fit(const int* __restrict__ offs, const int* __restrict__ csr,
                      const float* __restrict__ a_s, const float* __restrict__ fitp,
                      float* __restrict__ fit){
  int i = blockIdx.x * 256 + threadIdx.x;
  float f = fitp[i];
  int e1 = offs[i + 1];
  for(int e = offs[i]; e < e1; e++){
    f += a_s[csr[e]];
  }
  fit[i] = 1.f / (1.f + __expf(-f));
}

// ---- per-graph top-K + sum of xc*fit over selected -------------------------
template<typename T>
__launch_bounds__(512)
__global__ void k_select(const float* __restrict__ fit, const T* __restrict__ xc,
                         float* __restrict__ gsum){
  __shared__ float fl[NPGC];
  __shared__ int   sel[NPGC];
  __shared__ float part[NPGC];
  int g = blockIdx.x, t = threadIdx.x;
  fl[t] = fit[g * NPGC + t];
  __syncthreads();
  float ft = fl[t];
  int r = 0;
  for(int j = 0; j < NPGC; j++){
    float fj = fl[j];
    if(fj > ft || (fj == ft && j < t)) r++;
  }
  sel[t] = (r < KSEL) ? 1 : 0;
  __syncthreads();
  int c = t & (CC - 1), grp = t >> 7;
  float acc = 0.f;
  int nb = grp * 128;
  for(int n = nb; n < nb + 128; n++){
    if(sel[n]) acc = fmaf(ldh(&xc[((size_t)g * NPGC + n) * CC + c]), fl[n], acc);
  }
  part[t] = acc;
  __syncthreads();
  if(t < CC) gsum[g * CC + t] = part[t] + part[t + 128] + part[t + 256] + part[t + 384];
}

// ---- out[g] = (gsum/K) @ W2 + b2  (f32 out) --------------------------------
__global__ void k_out(const float* __restrict__ gsum, const float* __restrict__ wt,
                      const int* __restrict__ flags, float* __restrict__ out){
  __shared__ float gs[CC];
  int g = blockIdx.x, t = threadIdx.x;
  gs[t] = gsum[g * CC + t] * (1.f / (float)KSEL);
  __syncthreads();
  float acc = wt[OFF_b2 + t];
  for(int k = 0; k < CC; k++) acc = fmaf(gs[k], wt[OFF_W2 + k * CC + t], acc);
  if(!(fabsf(acc) < 1e30f)) acc = 7.0f + (float)flags[0];
  out[g * CC + t] = acc;
}

extern "C" void kernel_launch(void* const* d_in, const int* in_sizes, int n_in,
                              void* d_out, int out_size, void* d_ws, size_t ws_size,
                              hipStream_t stream){
  const void* x   = d_in[0];
  const void* W1  = d_in[1];
  const void* b1  = d_in[2];
  const void* Wp  = d_in[3];
  const void* bp  = d_in[4];
  const void* Wa  = d_in[5];
  const void* ba  = d_in[6];
  const void* Wl1 = d_in[7];
  const void* bl1 = d_in[8];
  const void* Wl2 = d_in[9];
  const void* Wl3 = d_in[10];
  const void* bl3 = d_in[11];
  const void* W2  = d_in[12];
  const void* b2  = d_in[13];
  const int* ei   = (const int*)d_in[14];
  float* out = (float*)d_out;

  char* base = (char*)d_ws;
  size_t off = 0;
  #define TAKE(bytes) (off += (bytes), (void*)(base + off - (bytes)))
  float* hs    = (float*)TAKE((size_t)NN * 4);
  float* a_s   = (float*)TAKE((size_t)NN * 4);
  float* fitp  = (float*)TAKE((size_t)NN * 4);
  float* fit   = (float*)TAKE((size_t)NN * 4);
  float* vvec  = (float*)TAKE(128 * 4);
  float* cval  = (float*)TAKE(128 * 4);
  float* gsum  = (float*)TAKE((size_t)BB * CC * 4);
  int*   offs  = (int*)TAKE((size_t)(NN + 128) * 4);
  int*   deg   = (int*)TAKE((size_t)NN * 4);      // reused as cursor
  int*   bsum  = (int*)TAKE(256 * 4);
  int*   bexc  = (int*)TAKE(256 * 4);
  int*   scr   = (int*)TAKE(256 * 4);
  float* wt    = (float*)TAKE((size_t)(WT_TOTAL + 64) * 4);
  int*   flags = (int*)TAKE(64 * 4);
  int*   csr   = (int*)TAKE((size_t)EE * 4);
  size_t fixed = off;
  #undef TAKE
  int* cursor = deg;

  bool f32plan = (ws_size >= fixed + (size_t)2 * NN * CC * 4);

  k_detect<<<1, 256, 0, stream>>>((const unsigned int*)x, flags);
  k_convert<<<(WT_TOTAL + 255) / 256, 256, 0, stream>>>(W1, Wp, W2, b1, bp, b2,
                                                        Wl1, Wl2, Wl3, Wa, ba,
                                                        bl1, bl3, wt, flags);
  k_prep<<<1, 128, 0, stream>>>(wt, vvec, cval);
  k_zero<<<NN / 256, 256, 0, stream>>>(deg);
  k_count<<<EE / 256, 256, 0, stream>>>(ei, deg);
  k_scan_block<<<256, 256, 0, stream>>>(deg, offs, bsum);
  k_scan_block<<<1, 256, 0, stream>>>(bsum, bexc, scr);
  k_scan_add<<<256, 256, 0, stream>>>(bexc, offs, cursor);
  k_fill<<<EE / 256, 256, 0, stream>>>(ei, cursor, csr);

  if(f32plan){
    float* h  = (float*)(base + fixed);
    float* xc = h + (size_t)NN * CC;
    k_gemm<float><<<2048, 128, 0, stream>>>(x, wt, flags, h, hs);
    k_edge_f32<<<NN / 4, 256, 0, stream>>>(h, hs, offs, csr, vvec, cval, wt,
                                           xc, a_s, fitp);
    k_fit<<<NN / 256, 256, 0, stream>>>(offs, csr, a_s, fitp, fit);
    k_select<float><<<BB, 512, 0, stream>>>(fit, xc, gsum);
  }else{
    ushort_t* h  = (ushort_t*)(base + fixed);
    ushort_t* xc = h + (size_t)NN * CC;
    k_gemm<ushort_t><<<2048, 128, 0, stream>>>(x, wt, flags, h, hs);
    k_edge<ushort_t><<<NN / 4, 256, 0, stream>>>(h, hs, offs, csr, vvec, cval, wt,
                                                 xc, a_s, fitp);
    k_fit<<<NN / 256, 256, 0, stream>>>(offs, csr, a_s, fitp, fit);
    k_select<ushort_t><<<BB, 512, 0, stream>>>(fit, xc, gsum);
  }
  k_out<<<BB, 128, 0, stream>>>(gsum, wt, flags, out);
}